// Round 2
// baseline (591.919 us; speedup 1.0000x reference)
//
#include <hip/hip_runtime.h>
#include <math.h>
#include <float.h>

#define BATCH 128
#define SEQ 64
#define IN 320
#define OUT 64
#define ITEM 256
#define HID 1024
#define OH 192
#define T65 65
#define KC 32
#define LDW 36   // LDS row stride (floats): 36 % 32 == 4 -> conflict-free b128, 16B aligned

__device__ __forceinline__ void bett(float& bv, int& bh, float v, int h) {
  if (v > bv || (v == bv && h < bh)) { bv = v; bh = h; }
}

// ---------------------------------------------------------------------------
// Register-tiled f32 GEMM core. R = rows-per-lane (8 for W tiles, 2 for X tile).
// Lane tile: R rows x 8 cols (+ R query accs). Per 4k: 17 ds_read_b128, 288 FMA.
// ---------------------------------------------------------------------------
template<int R>
__device__ __forceinline__ void gemm_body(
    const float* __restrict__ wbase, int wstride, int wrows,
    const float* __restrict__ xcb, const float* __restrict__ xqb,
    float* __restrict__ Ws, float* __restrict__ Xs,
    int tid, int lane, float (&acc)[R][8], float (&accq)[R])
{
  const int rg = lane >> 3, cg = lane & 7;
  const int wv = tid >> 6;
  const int rowbase = wv * (8 * R);   // 64 rows/wave (R=8) or 16 (R=2)

  for (int kc = 0; kc < ITEM; kc += KC) {
    __syncthreads();
    // stage W rows (row-major, stride LDW)
    const int nunit = wrows * (KC / 4);
    for (int u = tid; u < nunit; u += 256) {
      const int row = u >> 3, kq = (u & 7) << 2;
      const float4 v = *reinterpret_cast<const float4*>(wbase + (size_t)row * wstride + kc + kq);
      *reinterpret_cast<float4*>(&Ws[row * LDW + kq]) = v;
    }
    // stage x rows 0..63 (x_item) + row 64 (query)
    for (int u = tid; u < T65 * (KC / 4); u += 256) {
      const int row = u >> 3, kq = (u & 7) << 2;
      const float* src = (row < 64) ? (xcb + (size_t)row * IN) : xqb;
      const float4 v = *reinterpret_cast<const float4*>(src + kc + kq);
      *reinterpret_cast<float4*>(&Xs[row * LDW + kq]) = v;
    }
    __syncthreads();

    #pragma unroll
    for (int ks = 0; ks < KC; ks += 4) {
      float4 wf[R];
      #pragma unroll
      for (int i = 0; i < R; ++i)
        wf[i] = *reinterpret_cast<const float4*>(&Ws[(rowbase + rg + 8 * i) * LDW + ks]);
      const float4 qf = *reinterpret_cast<const float4*>(&Xs[64 * LDW + ks]);
      #pragma unroll
      for (int j = 0; j < 8; ++j) {
        const float4 xf = *reinterpret_cast<const float4*>(&Xs[(cg + 8 * j) * LDW + ks]);
        #pragma unroll
        for (int i = 0; i < R; ++i)
          acc[i][j] = fmaf(wf[i].w, xf.w, fmaf(wf[i].z, xf.z,
                      fmaf(wf[i].y, xf.y, fmaf(wf[i].x, xf.x, acc[i][j]))));
      }
      #pragma unroll
      for (int i = 0; i < R; ++i)
        accq[i] = fmaf(wf[i].w, qf.w, fmaf(wf[i].z, qf.z,
                  fmaf(wf[i].y, qf.y, fmaf(wf[i].x, qf.x, accq[i]))));
    }
  }
}

// grid (5, BATCH), block 256. tiles 0..3: 256 W_hi rows each -> G.
// tile 4: the 64 x_item rows -> X (Gram matrix). Query col fused (col 64).
__global__ __launch_bounds__(256) void k_gemm(
    const float* __restrict__ W_hi, const float* __restrict__ x_c,
    const float* __restrict__ x_q, float* __restrict__ G, float* __restrict__ X)
{
  const int b = blockIdx.y, tile = blockIdx.x;
  const int tid = threadIdx.x, lane = tid & 63;
  const int rg = lane >> 3, cg = lane & 7, wv = tid >> 6;
  __shared__ float Ws[256 * LDW];   // 36,864 B
  __shared__ float Xs[T65 * LDW];   //  9,360 B
  const float* xcb = x_c + (size_t)b * SEQ * IN;
  const float* xqb = x_q + (size_t)b * ITEM;

  if (tile < 4) {
    float acc[8][8] = {}; float accq[8] = {};
    gemm_body<8>(W_hi + ((size_t)b * HID + tile * 256) * ITEM, ITEM, 256,
                 xcb, xqb, Ws, Xs, tid, lane, acc, accq);
    const int hb = tile * 256 + wv * 64 + rg;
    #pragma unroll
    for (int i = 0; i < 8; ++i) {
      const int h = hb + 8 * i;
      #pragma unroll
      for (int j = 0; j < 8; ++j)
        G[((size_t)b * T65 + (cg + 8 * j)) * HID + h] = acc[i][j];
      if (cg == 0) G[((size_t)b * T65 + 64) * HID + h] = accq[i];
    }
  } else {
    float acc[2][8] = {}; float accq[2] = {};
    gemm_body<2>(xcb, IN, 64, xcb, xqb, Ws, Xs, tid, lane, acc, accq);
    const int sb = wv * 16 + rg;
    #pragma unroll
    for (int i = 0; i < 2; ++i) {
      const int s = sb + 8 * i;
      #pragma unroll
      for (int j = 0; j < 8; ++j)
        X[((size_t)b * T65 + (cg + 8 * j)) * SEQ + s] = acc[i][j];
      if (cg == 0) X[((size_t)b * T65 + 64) * SEQ + s] = accq[i];
    }
  }
}

// ---------------------------------------------------------------------------
// Single-wave sequential scan. grid BATCH, block 64. Register-only state:
// vmask bit i = row (lane+64i) virgin; lane s owns slot s (myrow = row last
// written at step s, if still current). Butterfly argmax, no barriers in loop.
// ---------------------------------------------------------------------------
__global__ __launch_bounds__(64) void k_scan(
    const float* __restrict__ G, const float* __restrict__ X,
    float* __restrict__ a_mod, float* __restrict__ t_a)
{
  const int b = blockIdx.x, lane = threadIdx.x;
  __shared__ float Xs[T65 * SEQ];
  {
    const float4* Xsrc = reinterpret_cast<const float4*>(X + (size_t)b * T65 * SEQ);
    float4* Xd = reinterpret_cast<float4*>(Xs);
    for (int i = lane; i < T65 * SEQ / 4; i += 64) Xd[i] = Xsrc[i];
  }
  const float* Gb = G + (size_t)b * T65 * HID;
  float gcur[16];
  #pragma unroll
  for (int i = 0; i < 16; ++i) gcur[i] = Gb[lane + 64 * i];
  __syncthreads();

  unsigned vmask = 0xFFFFu;
  int myrow = 0x7FFFFFFF;
  bool active = false;

  for (int t = 0; t < SEQ; ++t) {
    const float* Gn = Gb + (size_t)(t + 1) * HID;
    float gnext[16];
    #pragma unroll
    for (int i = 0; i < 16; ++i) gnext[i] = Gn[lane + 64 * i];

    float bv = -FLT_MAX; int bh = 0x7FFFFFFF;
    #pragma unroll
    for (int i = 0; i < 16; ++i) {
      const float v = ((vmask >> i) & 1u) ? gcur[i] : -FLT_MAX;
      bett(bv, bh, v, lane + (i << 6));
    }
    {
      const float v = active ? Xs[t * SEQ + lane] : -FLT_MAX;
      bett(bv, bh, v, myrow);
    }
    #pragma unroll
    for (int m = 1; m < 64; m <<= 1) {
      const float ov = __shfl_xor(bv, m, 64);
      const int oh = __shfl_xor(bh, m, 64);
      bett(bv, bh, ov, oh);
    }
    // winner bh known by all lanes; update register state
    if (active && myrow == bh) active = false;     // row re-won: old slot dies
    if (lane == t) { active = true; myrow = bh; }  // slot t now holds winner
    if ((bh & 63) == lane) vmask &= ~(1u << (bh >> 6));
    #pragma unroll
    for (int i = 0; i < 16; ++i) gcur[i] = gnext[i];
  }

  // gcur = G row 64 = query logits of virgin rows; touched logits from Xs row 64
  float e[16];
  float mx = -FLT_MAX;
  #pragma unroll
  for (int i = 0; i < 16; ++i) {
    e[i] = ((vmask >> i) & 1u) ? gcur[i] : -FLT_MAX;
    mx = fmaxf(mx, e[i]);
  }
  const float lt = active ? Xs[64 * SEQ + lane] : -FLT_MAX;
  mx = fmaxf(mx, lt);
  #pragma unroll
  for (int m = 1; m < 64; m <<= 1) mx = fmaxf(mx, __shfl_xor(mx, m, 64));
  float ssum = 0.f;
  #pragma unroll
  for (int i = 0; i < 16; ++i) {
    e[i] = ((vmask >> i) & 1u) ? expf(e[i] - mx) : 0.f;
    ssum += e[i];
  }
  const float et = active ? expf(lt - mx) : 0.f;
  ssum += et;
  #pragma unroll
  for (int m = 1; m < 64; m <<= 1) ssum += __shfl_xor(ssum, m, 64);
  const float inv = 1.f / ssum;
  #pragma unroll
  for (int i = 0; i < 16; ++i)
    a_mod[(size_t)b * HID + lane + 64 * i] = e[i] * inv;   // 0 for touched rows
  t_a[b * SEQ + lane] = et * inv;                          // 0 for inactive slots
}

// ---------------------------------------------------------------------------
// Partial matvecs with a_mod (touched rows zeroed). grid (4, BATCH), block 256.
// ---------------------------------------------------------------------------
__global__ __launch_bounds__(256) void k_partial(
    const float* __restrict__ W_oh, const float* __restrict__ W_re,
    const float* __restrict__ a_mod, float* __restrict__ p_out, float* __restrict__ p_re)
{
  const int b = blockIdx.y, p = blockIdx.x;
  const int tid = threadIdx.x;
  const int h0 = p * 256;
  __shared__ float as[256];
  as[tid] = a_mod[(size_t)b * HID + h0 + tid];
  __syncthreads();

  const int wv = tid >> 6, lane = tid & 63;
  if (wv < 3) {
    const int c = tid;   // 0..191
    const float* Wr = W_re + ((size_t)b * HID + h0) * OH + c;
    float acc = 0.f;
    #pragma unroll 8
    for (int h = 0; h < 256; ++h)
      acc = fmaf(Wr[(size_t)h * OH], as[h], acc);
    p_re[((size_t)b * 4 + p) * OH + c] = acc;
  } else {
    for (int o = 0; o < 64; ++o) {
      const float4 w4 = *reinterpret_cast<const float4*>(
          W_oh + ((size_t)b * OUT + o) * HID + h0 + lane * 4);
      const float* ap = &as[lane * 4];
      float acc = w4.x * ap[0] + w4.y * ap[1] + w4.z * ap[2] + w4.w * ap[3];
      #pragma unroll
      for (int m = 1; m < 64; m <<= 1) acc += __shfl_xor(acc, m, 64);
      if (lane == 0) p_out[((size_t)b * 4 + p) * OUT + o] = acc;
    }
  }
}

// ---------------------------------------------------------------------------
// Combine partials + dense 64-slot corrections. grid BATCH, block 256.
// ---------------------------------------------------------------------------
__global__ __launch_bounds__(256) void k_final(
    const float* __restrict__ x_c, const float* __restrict__ ctx,
    const float* __restrict__ p_out, const float* __restrict__ p_re,
    const float* __restrict__ t_a, float* __restrict__ out)
{
  const int b = blockIdx.x, tid = threadIdx.x;
  __shared__ float sa[SEQ];
  if (tid < SEQ) sa[tid] = t_a[b * SEQ + tid];
  __syncthreads();
  if (tid < OUT) {
    const int o = tid;
    float acc = 0.f;
    #pragma unroll
    for (int p = 0; p < 4; ++p) acc += p_out[((size_t)b * 4 + p) * OUT + o];
    for (int j = 0; j < SEQ; ++j) {
      const float w = sa[j];
      if (w != 0.f) acc = fmaf(x_c[((size_t)b * SEQ + j) * IN + ITEM + o], w, acc);
    }
    out[(size_t)b * OUT + o] = acc;
  } else if (tid < OUT + OH) {
    const int c = tid - OUT;
    float acc = 0.f;
    #pragma unroll
    for (int p = 0; p < 4; ++p) acc += p_re[((size_t)b * 4 + p) * OH + c];
    for (int j = 0; j < SEQ; ++j) {
      const float w = sa[j];
      if (w != 0.f) acc = fmaf(ctx[((size_t)b * SEQ + j) * OH + c], w, acc);
    }
    out[(size_t)BATCH * OUT + (size_t)b * OH + c] = acc;
  }
}

// ---------------------------------------------------------------------------
extern "C" void kernel_launch(void* const* d_in, const int* in_sizes, int n_in,
                              void* d_out, int out_size, void* d_ws, size_t ws_size,
                              hipStream_t stream)
{
  const float* x_c  = (const float*)d_in[0];   // 128 x 64 x 320
  const float* x_q  = (const float*)d_in[1];   // 128 x 256
  const float* ctx  = (const float*)d_in[2];   // 128 x 64 x 192
  const float* W_hi = (const float*)d_in[3];   // 128 x 1024 x 256
  const float* W_oh = (const float*)d_in[4];   // 128 x 64 x 1024
  const float* W_re = (const float*)d_in[5];   // 128 x 1024 x 192

  char* ws = (char*)d_ws;
  float* G     = (float*)(ws);                 // 128*65*1024*4 = 34,078,720
  float* X     = (float*)(ws + 34078720);      // 128*65*64*4   =  2,129,920
  float* a_mod = (float*)(ws + 36208640);      // 128*1024*4    =    524,288
  float* t_a   = (float*)(ws + 36732928);      // 128*64*4      =     32,768
  float* p_out = (float*)(ws + 36765696);      // 128*4*64*4    =    131,072
  float* p_re  = (float*)(ws + 36896768);      // 128*4*192*4   =    393,216

  k_gemm<<<dim3(5, BATCH), 256, 0, stream>>>(W_hi, x_c, x_q, G, X);
  k_scan<<<dim3(BATCH), 64, 0, stream>>>(G, X, a_mod, t_a);
  k_partial<<<dim3(4, BATCH), 256, 0, stream>>>(W_oh, W_re, a_mod, p_out, p_re);
  k_final<<<dim3(BATCH), 256, 0, stream>>>(x_c, ctx, p_out, p_re, t_a, (float*)d_out);
}

// Round 3
// 500.680 us; speedup vs baseline: 1.1822x; 1.1822x over previous
//
#include <hip/hip_runtime.h>
#include <math.h>
#include <float.h>

#define BATCH 128
#define SEQ 64
#define IN 320
#define OUT 64
#define ITEM 256
#define HID 1024
#define OH 192
#define T65 65
#define KC 32
#define LDW 36   // LDS row stride (floats): 36 % 32 == 4 -> conflict-free b128, 16B aligned

__device__ __forceinline__ void bett(float& bv, int& bh, float v, int h) {
  if (v > bv || (v == bv && h < bh)) { bv = v; bh = h; }
}

// ---------------------------------------------------------------------------
// Register-tiled f32 GEMM core. R = rows-per-lane (8 for W tiles, 2 for X tile).
// Lane tile: R rows x 8 cols (+ R query accs). Per 4k: 17 ds_read_b128, 288 FMA.
// Staging loops fully unrolled (compile-time trip counts) so global loads batch
// ahead of the ds_writes; ks loop unroll 2 to keep the hot body ~5 KB.
// ---------------------------------------------------------------------------
template<int R, int WROWS>
__device__ __forceinline__ void gemm_body(
    const float* __restrict__ wbase, int wstride,
    const float* __restrict__ xcb, const float* __restrict__ xqb,
    float* __restrict__ Ws, float* __restrict__ Xs,
    int tid, int lane, float (&acc)[R][8], float (&accq)[R])
{
  const int rg = lane >> 3, cg = lane & 7;
  const int wv = tid >> 6;
  const int rowbase = wv * (8 * R);   // 64 rows/wave (R=8) or 16 (R=2)

  for (int kc = 0; kc < ITEM; kc += KC) {
    __syncthreads();
    // stage W rows (row-major, stride LDW) — unrolled, loads batch before writes
    #pragma unroll
    for (int u0 = 0; u0 < WROWS * (KC / 4); u0 += 256) {
      const int u = u0 + tid;
      const int row = u >> 3, kq = (u & 7) << 2;
      const float4 v = *reinterpret_cast<const float4*>(wbase + (size_t)row * wstride + kc + kq);
      *reinterpret_cast<float4*>(&Ws[row * LDW + kq]) = v;
    }
    // stage x rows 0..63 (x_item) + row 64 (query)
    #pragma unroll
    for (int u0 = 0; u0 < T65 * (KC / 4); u0 += 256) {
      const int u = u0 + tid;
      if (u < T65 * (KC / 4)) {
        const int row = u >> 3, kq = (u & 7) << 2;
        const float* src = (row < 64) ? (xcb + (size_t)row * IN) : xqb;
        const float4 v = *reinterpret_cast<const float4*>(src + kc + kq);
        *reinterpret_cast<float4*>(&Xs[row * LDW + kq]) = v;
      }
    }
    __syncthreads();

    #pragma unroll 2
    for (int ks = 0; ks < KC; ks += 4) {
      float4 wf[R];
      #pragma unroll
      for (int i = 0; i < R; ++i)
        wf[i] = *reinterpret_cast<const float4*>(&Ws[(rowbase + rg + 8 * i) * LDW + ks]);
      const float4 qf = *reinterpret_cast<const float4*>(&Xs[64 * LDW + ks]);
      #pragma unroll
      for (int j = 0; j < 8; ++j) {
        const float4 xf = *reinterpret_cast<const float4*>(&Xs[(cg + 8 * j) * LDW + ks]);
        #pragma unroll
        for (int i = 0; i < R; ++i)
          acc[i][j] = fmaf(wf[i].w, xf.w, fmaf(wf[i].z, xf.z,
                      fmaf(wf[i].y, xf.y, fmaf(wf[i].x, xf.x, acc[i][j]))));
      }
      #pragma unroll
      for (int i = 0; i < R; ++i)
        accq[i] = fmaf(wf[i].w, qf.w, fmaf(wf[i].z, qf.z,
                  fmaf(wf[i].y, qf.y, fmaf(wf[i].x, qf.x, accq[i]))));
    }
  }
}

// grid (5, BATCH), block 256. tiles 0..3: 256 W_hi rows each -> G.
// tile 4: the 64 x_item rows -> X (Gram matrix). Query col fused (col 64).
__global__ __launch_bounds__(256, 4) void k_gemm(
    const float* __restrict__ W_hi, const float* __restrict__ x_c,
    const float* __restrict__ x_q, float* __restrict__ G, float* __restrict__ X)
{
  const int b = blockIdx.y, tile = blockIdx.x;
  const int tid = threadIdx.x, lane = tid & 63;
  const int rg = lane >> 3, cg = lane & 7, wv = tid >> 6;
  __shared__ float Ws[256 * LDW];   // 36,864 B
  __shared__ float Xs[T65 * LDW];   //  9,360 B
  const float* xcb = x_c + (size_t)b * SEQ * IN;
  const float* xqb = x_q + (size_t)b * ITEM;

  if (tile < 4) {
    float acc[8][8] = {}; float accq[8] = {};
    gemm_body<8, 256>(W_hi + ((size_t)b * HID + tile * 256) * ITEM, ITEM,
                      xcb, xqb, Ws, Xs, tid, lane, acc, accq);
    const int hb = tile * 256 + wv * 64 + rg;
    #pragma unroll
    for (int i = 0; i < 8; ++i) {
      const int h = hb + 8 * i;
      #pragma unroll
      for (int j = 0; j < 8; ++j)
        G[((size_t)b * T65 + (cg + 8 * j)) * HID + h] = acc[i][j];
      if (cg == 0) G[((size_t)b * T65 + 64) * HID + h] = accq[i];
    }
  } else {
    float acc[2][8] = {}; float accq[2] = {};
    gemm_body<2, 64>(xcb, IN, xcb, xqb, Ws, Xs, tid, lane, acc, accq);
    const int sb = wv * 16 + rg;
    #pragma unroll
    for (int i = 0; i < 2; ++i) {
      const int s = sb + 8 * i;
      #pragma unroll
      for (int j = 0; j < 8; ++j)
        X[((size_t)b * T65 + (cg + 8 * j)) * SEQ + s] = acc[i][j];
      if (cg == 0) X[((size_t)b * T65 + 64) * SEQ + s] = accq[i];
    }
  }
}

// ---------------------------------------------------------------------------
// Single-wave sequential scan. grid BATCH, block 64. Register-only state:
// vmask bit i = row (lane+64i) virgin; lane s owns slot s (myrow = row last
// written at step s, if still current). Butterfly argmax, no barriers in loop.
// Depth-2 G-row prefetch: two reduce phases cover one L2/L3 load latency.
// ---------------------------------------------------------------------------
__global__ __launch_bounds__(64) void k_scan(
    const float* __restrict__ G, const float* __restrict__ X,
    float* __restrict__ a_mod, float* __restrict__ t_a)
{
  const int b = blockIdx.x, lane = threadIdx.x;
  __shared__ float Xs[T65 * SEQ];
  {
    const float4* Xsrc = reinterpret_cast<const float4*>(X + (size_t)b * T65 * SEQ);
    float4* Xd = reinterpret_cast<float4*>(Xs);
    for (int i = lane; i < T65 * SEQ / 4; i += 64) Xd[i] = Xsrc[i];
  }
  const float* Gb = G + (size_t)b * T65 * HID;
  float g0[16], g1[16];
  #pragma unroll
  for (int i = 0; i < 16; ++i) g0[i] = Gb[lane + 64 * i];
  #pragma unroll
  for (int i = 0; i < 16; ++i) g1[i] = Gb[HID + lane + 64 * i];
  __syncthreads();

  unsigned vmask = 0xFFFFu;
  int myrow = 0x7FFFFFFF;
  bool active = false;

  for (int t = 0; t < SEQ; ++t) {
    const int tn = (t + 2 < 64) ? (t + 2) : 64;
    const float* Gn = Gb + (size_t)tn * HID;
    float g2[16];
    #pragma unroll
    for (int i = 0; i < 16; ++i) g2[i] = Gn[lane + 64 * i];

    float bv = -FLT_MAX; int bh = 0x7FFFFFFF;
    #pragma unroll
    for (int i = 0; i < 16; ++i) {
      const float v = ((vmask >> i) & 1u) ? g0[i] : -FLT_MAX;
      bett(bv, bh, v, lane + (i << 6));
    }
    {
      const float v = active ? Xs[t * SEQ + lane] : -FLT_MAX;
      bett(bv, bh, v, myrow);
    }
    #pragma unroll
    for (int m = 1; m < 64; m <<= 1) {
      const float ov = __shfl_xor(bv, m, 64);
      const int oh = __shfl_xor(bh, m, 64);
      bett(bv, bh, ov, oh);
    }
    // winner bh known by all lanes; update register state
    if (active && myrow == bh) active = false;     // row re-won: old slot dies
    if (lane == t) { active = true; myrow = bh; }  // slot t now holds winner
    if ((bh & 63) == lane) vmask &= ~(1u << (bh >> 6));
    #pragma unroll
    for (int i = 0; i < 16; ++i) { g0[i] = g1[i]; g1[i] = g2[i]; }
  }

  // g0 now holds G row 64 = query logits of virgin rows; touched from Xs row 64
  float e[16];
  float mx = -FLT_MAX;
  #pragma unroll
  for (int i = 0; i < 16; ++i) {
    e[i] = ((vmask >> i) & 1u) ? g0[i] : -FLT_MAX;
    mx = fmaxf(mx, e[i]);
  }
  const float lt = active ? Xs[64 * SEQ + lane] : -FLT_MAX;
  mx = fmaxf(mx, lt);
  #pragma unroll
  for (int m = 1; m < 64; m <<= 1) mx = fmaxf(mx, __shfl_xor(mx, m, 64));
  float ssum = 0.f;
  #pragma unroll
  for (int i = 0; i < 16; ++i) {
    e[i] = ((vmask >> i) & 1u) ? expf(e[i] - mx) : 0.f;
    ssum += e[i];
  }
  const float et = active ? expf(lt - mx) : 0.f;
  ssum += et;
  #pragma unroll
  for (int m = 1; m < 64; m <<= 1) ssum += __shfl_xor(ssum, m, 64);
  const float inv = 1.f / ssum;
  #pragma unroll
  for (int i = 0; i < 16; ++i)
    a_mod[(size_t)b * HID + lane + 64 * i] = e[i] * inv;   // 0 for touched rows
  t_a[b * SEQ + lane] = et * inv;                          // 0 for inactive slots
}

// ---------------------------------------------------------------------------
// Partial matvecs with a_mod (touched rows zeroed). grid (4, BATCH), block 256.
// ---------------------------------------------------------------------------
__global__ __launch_bounds__(256) void k_partial(
    const float* __restrict__ W_oh, const float* __restrict__ W_re,
    const float* __restrict__ a_mod, float* __restrict__ p_out, float* __restrict__ p_re)
{
  const int b = blockIdx.y, p = blockIdx.x;
  const int tid = threadIdx.x;
  const int h0 = p * 256;
  __shared__ float as[256];
  as[tid] = a_mod[(size_t)b * HID + h0 + tid];
  __syncthreads();

  const int wv = tid >> 6, lane = tid & 63;
  if (wv < 3) {
    const int c = tid;   // 0..191
    const float* Wr = W_re + ((size_t)b * HID + h0) * OH + c;
    float acc = 0.f;
    #pragma unroll 16
    for (int h = 0; h < 256; ++h)
      acc = fmaf(Wr[(size_t)h * OH], as[h], acc);
    p_re[((size_t)b * 4 + p) * OH + c] = acc;
  } else {
    for (int o = 0; o < 64; ++o) {
      const float4 w4 = *reinterpret_cast<const float4*>(
          W_oh + ((size_t)b * OUT + o) * HID + h0 + lane * 4);
      const float* ap = &as[lane * 4];
      float acc = w4.x * ap[0] + w4.y * ap[1] + w4.z * ap[2] + w4.w * ap[3];
      #pragma unroll
      for (int m = 1; m < 64; m <<= 1) acc += __shfl_xor(acc, m, 64);
      if (lane == 0) p_out[((size_t)b * 4 + p) * OUT + o] = acc;
    }
  }
}

// ---------------------------------------------------------------------------
// Combine partials + dense 64-slot corrections. grid BATCH, block 256.
// ---------------------------------------------------------------------------
__global__ __launch_bounds__(256) void k_final(
    const float* __restrict__ x_c, const float* __restrict__ ctx,
    const float* __restrict__ p_out, const float* __restrict__ p_re,
    const float* __restrict__ t_a, float* __restrict__ out)
{
  const int b = blockIdx.x, tid = threadIdx.x;
  __shared__ float sa[SEQ];
  if (tid < SEQ) sa[tid] = t_a[b * SEQ + tid];
  __syncthreads();
  if (tid < OUT) {
    const int o = tid;
    float acc = 0.f;
    #pragma unroll
    for (int p = 0; p < 4; ++p) acc += p_out[((size_t)b * 4 + p) * OUT + o];
    for (int j = 0; j < SEQ; ++j) {
      const float w = sa[j];
      if (w != 0.f) acc = fmaf(x_c[((size_t)b * SEQ + j) * IN + ITEM + o], w, acc);
    }
    out[(size_t)b * OUT + o] = acc;
  } else if (tid < OUT + OH) {
    const int c = tid - OUT;
    float acc = 0.f;
    #pragma unroll
    for (int p = 0; p < 4; ++p) acc += p_re[((size_t)b * 4 + p) * OH + c];
    for (int j = 0; j < SEQ; ++j) {
      const float w = sa[j];
      if (w != 0.f) acc = fmaf(ctx[((size_t)b * SEQ + j) * OH + c], w, acc);
    }
    out[(size_t)BATCH * OUT + (size_t)b * OH + c] = acc;
  }
}

// ---------------------------------------------------------------------------
extern "C" void kernel_launch(void* const* d_in, const int* in_sizes, int n_in,
                              void* d_out, int out_size, void* d_ws, size_t ws_size,
                              hipStream_t stream)
{
  const float* x_c  = (const float*)d_in[0];   // 128 x 64 x 320
  const float* x_q  = (const float*)d_in[1];   // 128 x 256
  const float* ctx  = (const float*)d_in[2];   // 128 x 64 x 192
  const float* W_hi = (const float*)d_in[3];   // 128 x 1024 x 256
  const float* W_oh = (const float*)d_in[4];   // 128 x 64 x 1024
  const float* W_re = (const float*)d_in[5];   // 128 x 1024 x 192

  char* ws = (char*)d_ws;
  float* G     = (float*)(ws);                 // 128*65*1024*4 = 34,078,720
  float* X     = (float*)(ws + 34078720);      // 128*65*64*4   =  2,129,920
  float* a_mod = (float*)(ws + 36208640);      // 128*1024*4    =    524,288
  float* t_a   = (float*)(ws + 36732928);      // 128*64*4      =     32,768
  float* p_out = (float*)(ws + 36765696);      // 128*4*64*4    =    131,072
  float* p_re  = (float*)(ws + 36896768);      // 128*4*192*4   =    393,216

  k_gemm<<<dim3(5, BATCH), 256, 0, stream>>>(W_hi, x_c, x_q, G, X);
  k_scan<<<dim3(BATCH), 64, 0, stream>>>(G, X, a_mod, t_a);
  k_partial<<<dim3(4, BATCH), 256, 0, stream>>>(W_oh, W_re, a_mod, p_out, p_re);
  k_final<<<dim3(BATCH), 256, 0, stream>>>(x_c, ctx, p_out, p_re, t_a, (float*)d_out);
}

// Round 4
// 482.327 us; speedup vs baseline: 1.2272x; 1.0381x over previous
//
#include <hip/hip_runtime.h>
#include <math.h>
#include <float.h>

#define BATCH 128
#define SEQ 64
#define IN 320
#define OUT 64
#define ITEM 256
#define HID 1024
#define OH 192
#define T65 65
#define KC 32
#define LDW 36   // LDS row stride (floats): 36 % 32 == 4 -> conflict-free b128, 16B aligned

__device__ __forceinline__ void bett(float& bv, int& bh, float v, int h) {
  if (v > bv || (v == bv && h < bh)) { bv = v; bh = h; }
}
__device__ __forceinline__ float f4c(const float4& v, int i) {
  return i == 0 ? v.x : (i == 1 ? v.y : (i == 2 ? v.z : v.w));
}

// ---------------------------------------------------------------------------
// Register-tiled f32 GEMM core. R rows/lane x 8 cols (+R query accs).
// 128-row W tiles (R=4): per ks step 13 ds_read_b128 (156cy) vs 144 FMA (288cy)
// -> VALU-bound with 0 bank conflicts; small LDS for 4 blocks/CU residency.
// ---------------------------------------------------------------------------
template<int R, int WROWS>
__device__ __forceinline__ void gemm_body(
    const float* __restrict__ wbase, int wstride,
    const float* __restrict__ xcb, const float* __restrict__ xqb,
    float* __restrict__ Ws, float* __restrict__ Xs,
    int tid, int lane, float (&acc)[R][8], float (&accq)[R])
{
  const int rg = lane >> 3, cg = lane & 7;
  const int wv = tid >> 6;
  const int rowbase = wv * (8 * R);

  for (int kc = 0; kc < ITEM; kc += KC) {
    __syncthreads();
    #pragma unroll
    for (int u0 = 0; u0 < WROWS * (KC / 4); u0 += 256) {
      const int u = u0 + tid;
      const int row = u >> 3, kq = (u & 7) << 2;
      const float4 v = *reinterpret_cast<const float4*>(wbase + (size_t)row * wstride + kc + kq);
      *reinterpret_cast<float4*>(&Ws[row * LDW + kq]) = v;
    }
    #pragma unroll
    for (int u0 = 0; u0 < T65 * (KC / 4); u0 += 256) {
      const int u = u0 + tid;
      if (u < T65 * (KC / 4)) {
        const int row = u >> 3, kq = (u & 7) << 2;
        const float* src = (row < 64) ? (xcb + (size_t)row * IN) : xqb;
        const float4 v = *reinterpret_cast<const float4*>(src + kc + kq);
        *reinterpret_cast<float4*>(&Xs[row * LDW + kq]) = v;
      }
    }
    __syncthreads();

    #pragma unroll 2
    for (int ks = 0; ks < KC; ks += 4) {
      float4 wf[R];
      #pragma unroll
      for (int i = 0; i < R; ++i)
        wf[i] = *reinterpret_cast<const float4*>(&Ws[(rowbase + rg + 8 * i) * LDW + ks]);
      const float4 qf = *reinterpret_cast<const float4*>(&Xs[64 * LDW + ks]);
      #pragma unroll
      for (int j = 0; j < 8; ++j) {
        const float4 xf = *reinterpret_cast<const float4*>(&Xs[(cg + 8 * j) * LDW + ks]);
        #pragma unroll
        for (int i = 0; i < R; ++i)
          acc[i][j] = fmaf(wf[i].w, xf.w, fmaf(wf[i].z, xf.z,
                      fmaf(wf[i].y, xf.y, fmaf(wf[i].x, xf.x, acc[i][j]))));
      }
      #pragma unroll
      for (int i = 0; i < R; ++i)
        accq[i] = fmaf(wf[i].w, qf.w, fmaf(wf[i].z, qf.z,
                  fmaf(wf[i].y, qf.y, fmaf(wf[i].x, qf.x, accq[i]))));
    }
  }
}

// grid (9, BATCH), block 256. tiles 0..7: 128 W_hi rows each -> G.
// tile 8: the 64 x_item rows -> X (Gram matrix). Query col fused (col 64).
__global__ __launch_bounds__(256, 4) void k_gemm(
    const float* __restrict__ W_hi, const float* __restrict__ x_c,
    const float* __restrict__ x_q, float* __restrict__ G, float* __restrict__ X)
{
  const int b = blockIdx.y, tile = blockIdx.x;
  const int tid = threadIdx.x, lane = tid & 63;
  const int rg = lane >> 3, cg = lane & 7, wv = tid >> 6;
  __shared__ float Ws[128 * LDW];   // 18,432 B
  __shared__ float Xs[T65 * LDW];   //  9,360 B
  const float* xcb = x_c + (size_t)b * SEQ * IN;
  const float* xqb = x_q + (size_t)b * ITEM;

  if (tile < 8) {
    float acc[4][8] = {}; float accq[4] = {};
    gemm_body<4, 128>(W_hi + ((size_t)b * HID + tile * 128) * ITEM, ITEM,
                      xcb, xqb, Ws, Xs, tid, lane, acc, accq);
    const int hb = tile * 128 + wv * 32 + rg;
    #pragma unroll
    for (int i = 0; i < 4; ++i) {
      const int h = hb + 8 * i;
      #pragma unroll
      for (int j = 0; j < 8; ++j)
        G[((size_t)b * T65 + (cg + 8 * j)) * HID + h] = acc[i][j];
      if (cg == 0) G[((size_t)b * T65 + 64) * HID + h] = accq[i];
    }
  } else {
    float acc[2][8] = {}; float accq[2] = {};
    gemm_body<2, 64>(xcb, IN, xcb, xqb, Ws, Xs, tid, lane, acc, accq);
    const int sb = wv * 16 + rg;
    #pragma unroll
    for (int i = 0; i < 2; ++i) {
      const int s = sb + 8 * i;
      #pragma unroll
      for (int j = 0; j < 8; ++j)
        X[((size_t)b * T65 + (cg + 8 * j)) * SEQ + s] = acc[i][j];
      if (cg == 0) X[((size_t)b * T65 + 64) * SEQ + s] = accq[i];
    }
  }
}

// ---------------------------------------------------------------------------
// Single-wave sequential scan. grid BATCH, block 64. Lane owns h = lane*16+r
// (r=0..15): G-row loads are 4 coalesced dwordx4/lane; lane order == h order,
// so value-only fmaxf butterfly + ballot/ffsll gives exact lowest-h argmax.
// Depth-3 role-rotated prefetch buffers (no register rotation copies).
// ---------------------------------------------------------------------------
__global__ __launch_bounds__(64) void k_scan(
    const float* __restrict__ G, const float* __restrict__ X,
    float* __restrict__ a_mod, float* __restrict__ t_a)
{
  const int b = blockIdx.x, lane = threadIdx.x;
  __shared__ float Xs[T65 * SEQ];
  {
    const float4* Xsrc = reinterpret_cast<const float4*>(X + (size_t)b * T65 * SEQ);
    float4* Xd = reinterpret_cast<float4*>(Xs);
    for (int i = lane; i < T65 * SEQ / 4; i += 64) Xd[i] = Xsrc[i];
  }
  const float* Gb = G + (size_t)b * T65 * HID;
  const int hbase = lane << 4;

  float4 gb0[4], gb1[4], gb2[4];
  {
    const float4* Gv0 = reinterpret_cast<const float4*>(Gb + 0 * HID + hbase);
    const float4* Gv1 = reinterpret_cast<const float4*>(Gb + 1 * HID + hbase);
    const float4* Gv2 = reinterpret_cast<const float4*>(Gb + 2 * HID + hbase);
    #pragma unroll
    for (int q = 0; q < 4; ++q) { gb0[q] = Gv0[q]; gb1[q] = Gv1[q]; gb2[q] = Gv2[q]; }
  }
  __syncthreads();

  unsigned vmask = 0xFFFFu;   // bit r: row hbase+r virgin
  int myrow = 0x7FFFFFFF;     // slot lane==t: row last written at step t
  bool active = false;

  auto step = [&](int t, float4 (&g)[4]) {
    // slot candidate (independent LDS read, issues early)
    const float sv = active ? Xs[t * SEQ + lane] : -FLT_MAX;
    // local 17-way scan (consumes g)
    float bv = -FLT_MAX; int bh = 0x7FFFFFFF;
    #pragma unroll
    for (int r = 0; r < 16; ++r) {
      const float v = ((vmask >> r) & 1u) ? f4c(g[r >> 2], r & 3) : -FLT_MAX;
      bett(bv, bh, v, hbase + r);
    }
    bett(bv, bh, sv, myrow);
    // g dead: issue prefetch of row t+3 into it (flies under the reduce)
    {
      const int rown = (t + 3 < 64) ? (t + 3) : 64;
      const float4* Gv = reinterpret_cast<const float4*>(Gb + (size_t)rown * HID + hbase);
      #pragma unroll
      for (int q = 0; q < 4; ++q) g[q] = Gv[q];
    }
    // value-only butterfly max
    float gm = bv;
    #pragma unroll
    for (int m = 1; m < 64; m <<= 1) gm = fmaxf(gm, __shfl_xor(gm, m, 64));
    const unsigned long long tied = __ballot(bv == gm);
    const int srcl = __ffsll(tied) - 1;
    const int winner = __shfl(bh, srcl, 64);
    // state update
    if (active && myrow == winner) active = false;
    if (lane == t) { active = true; myrow = winner; }
    if ((winner >> 4) == lane) vmask &= ~(1u << (winner & 15));
  };

  for (int tb = 0; tb < 63; tb += 3) {
    step(tb + 0, gb0);
    step(tb + 1, gb1);
    step(tb + 2, gb2);
  }
  step(63, gb0);
  // query row 64 sits in gb1 (loaded at t=61, untouched since)

  float e[16];
  float mx = -FLT_MAX;
  #pragma unroll
  for (int r = 0; r < 16; ++r) {
    e[r] = ((vmask >> r) & 1u) ? f4c(gb1[r >> 2], r & 3) : -FLT_MAX;
    mx = fmaxf(mx, e[r]);
  }
  const float lt = active ? Xs[64 * SEQ + lane] : -FLT_MAX;
  mx = fmaxf(mx, lt);
  #pragma unroll
  for (int m = 1; m < 64; m <<= 1) mx = fmaxf(mx, __shfl_xor(mx, m, 64));
  float ssum = 0.f;
  #pragma unroll
  for (int r = 0; r < 16; ++r) {
    e[r] = ((vmask >> r) & 1u) ? expf(e[r] - mx) : 0.f;
    ssum += e[r];
  }
  const float et = active ? expf(lt - mx) : 0.f;
  ssum += et;
  #pragma unroll
  for (int m = 1; m < 64; m <<= 1) ssum += __shfl_xor(ssum, m, 64);
  const float inv = 1.f / ssum;
  float4* Ad = reinterpret_cast<float4*>(a_mod + (size_t)b * HID + hbase);
  #pragma unroll
  for (int q = 0; q < 4; ++q) {
    float4 st;
    st.x = e[4 * q + 0] * inv; st.y = e[4 * q + 1] * inv;
    st.z = e[4 * q + 2] * inv; st.w = e[4 * q + 3] * inv;
    Ad[q] = st;
  }
  t_a[b * SEQ + lane] = et * inv;
}

// ---------------------------------------------------------------------------
// Reinst partials: grid (8, BATCH), block 192. Streams W_re (100 MB) once.
// ---------------------------------------------------------------------------
__global__ __launch_bounds__(192) void k_part_re(
    const float* __restrict__ W_re, const float* __restrict__ a_mod,
    float* __restrict__ p_re)
{
  const int b = blockIdx.y, p = blockIdx.x;
  const int tid = threadIdx.x;
  const int h0 = p * 128;
  __shared__ float as[128];
  if (tid < 128) as[tid] = a_mod[(size_t)b * HID + h0 + tid];
  __syncthreads();
  const int c = tid;   // 0..191, contiguous across row
  const float* Wr = W_re + ((size_t)b * HID + h0) * OH + c;
  float acc = 0.f;
  #pragma unroll 16
  for (int h = 0; h < 128; ++h)
    acc = fmaf(Wr[(size_t)h * OH], as[h], acc);
  p_re[((size_t)b * 8 + p) * OH + c] = acc;
}

// ---------------------------------------------------------------------------
// Out partials: grid (2, BATCH), block 256. float4 loads + butterfly reduce.
// ---------------------------------------------------------------------------
__global__ __launch_bounds__(256) void k_part_out(
    const float* __restrict__ W_oh, const float* __restrict__ a_mod,
    float* __restrict__ p_out)
{
  const int b = blockIdx.y, half = blockIdx.x;
  const int tid = threadIdx.x, wv = tid >> 6, lane = tid & 63;
  __shared__ float4 as4[256];
  as4[tid] = reinterpret_cast<const float4*>(a_mod + (size_t)b * HID)[tid];
  __syncthreads();
  const int o0 = half * 32 + wv * 8;
  #pragma unroll
  for (int oi = 0; oi < 8; ++oi) {
    const int o = o0 + oi;
    const float4* W4 = reinterpret_cast<const float4*>(W_oh + ((size_t)b * OUT + o) * HID);
    float acc = 0.f;
    #pragma unroll
    for (int k = 0; k < 4; ++k) {
      const float4 w = W4[lane + 64 * k];
      const float4 a = as4[lane + 64 * k];
      acc += w.x * a.x + w.y * a.y + w.z * a.z + w.w * a.w;
    }
    #pragma unroll
    for (int m = 1; m < 64; m <<= 1) acc += __shfl_xor(acc, m, 64);
    if (lane == 0) p_out[((size_t)b * 2 + half) * OUT + o] = acc;
  }
}

// ---------------------------------------------------------------------------
// Combine partials + dense 64-slot corrections. grid BATCH, block 256.
// ---------------------------------------------------------------------------
__global__ __launch_bounds__(256) void k_final(
    const float* __restrict__ x_c, const float* __restrict__ ctx,
    const float* __restrict__ p_out, const float* __restrict__ p_re,
    const float* __restrict__ t_a, float* __restrict__ out)
{
  const int b = blockIdx.x, tid = threadIdx.x;
  __shared__ float sa[SEQ];
  if (tid < SEQ) sa[tid] = t_a[b * SEQ + tid];
  __syncthreads();
  if (tid < OUT) {
    const int o = tid;
    float acc = p_out[((size_t)b * 2 + 0) * OUT + o] + p_out[((size_t)b * 2 + 1) * OUT + o];
    for (int j = 0; j < SEQ; ++j) {
      const float w = sa[j];
      if (w != 0.f) acc = fmaf(x_c[((size_t)b * SEQ + j) * IN + ITEM + o], w, acc);
    }
    out[(size_t)b * OUT + o] = acc;
  } else if (tid < OUT + OH) {
    const int c = tid - OUT;
    float acc = 0.f;
    #pragma unroll
    for (int p = 0; p < 8; ++p) acc += p_re[((size_t)b * 8 + p) * OH + c];
    for (int j = 0; j < SEQ; ++j) {
      const float w = sa[j];
      if (w != 0.f) acc = fmaf(ctx[((size_t)b * SEQ + j) * OH + c], w, acc);
    }
    out[(size_t)BATCH * OUT + (size_t)b * OH + c] = acc;
  }
}

// ---------------------------------------------------------------------------
extern "C" void kernel_launch(void* const* d_in, const int* in_sizes, int n_in,
                              void* d_out, int out_size, void* d_ws, size_t ws_size,
                              hipStream_t stream)
{
  const float* x_c  = (const float*)d_in[0];   // 128 x 64 x 320
  const float* x_q  = (const float*)d_in[1];   // 128 x 256
  const float* ctx  = (const float*)d_in[2];   // 128 x 64 x 192
  const float* W_hi = (const float*)d_in[3];   // 128 x 1024 x 256
  const float* W_oh = (const float*)d_in[4];   // 128 x 64 x 1024
  const float* W_re = (const float*)d_in[5];   // 128 x 1024 x 192

  char* ws = (char*)d_ws;
  float* G     = (float*)(ws);                 // 128*65*1024*4 = 34,078,720
  float* X     = (float*)(ws + 34078720);      // 128*65*64*4   =  2,129,920
  float* a_mod = (float*)(ws + 36208640);      // 128*1024*4    =    524,288
  float* t_a   = (float*)(ws + 36732928);      // 128*64*4      =     32,768
  float* p_out = (float*)(ws + 36765696);      // 128*2*64*4    =     65,536
  float* p_re  = (float*)(ws + 36831232);      // 128*8*192*4   =    786,432

  k_gemm<<<dim3(9, BATCH), 256, 0, stream>>>(W_hi, x_c, x_q, G, X);
  k_scan<<<dim3(BATCH), 64, 0, stream>>>(G, X, a_mod, t_a);
  k_part_re<<<dim3(8, BATCH), 192, 0, stream>>>(W_re, a_mod, p_re);
  k_part_out<<<dim3(2, BATCH), 256, 0, stream>>>(W_oh, a_mod, p_out);
  k_final<<<dim3(BATCH), 256, 0, stream>>>(x_c, ctx, p_out, p_re, t_a, (float*)d_out);
}